// Round 8
// baseline (312.701 us; speedup 1.0000x reference)
//
#include <hip/hip_runtime.h>
#include <stdint.h>

#define N_TOK 4096
#define QDIM  1024
#define CDIM  1024
#define NH    8
#define DH    64
#define INNER 512
#define BATCH 2
#define N1    4097   // keys incl. background row
#define N1P   4128   // padded to /32
#define NJB   129    // real key tiles
#define NJBP  132    // padded; attn runs 66 iters x 2 tiles
#define VROWS 80     // 64 V dims + mask row + 15 unused
#define KTILE_SH 2048  // shorts per K tile: [2][32][32]
#define VTILE_SH 2560  // shorts per V tile: [80][32]

typedef __attribute__((ext_vector_type(8))) short short8;
typedef __attribute__((ext_vector_type(4))) float f32x4;
typedef __attribute__((ext_vector_type(4))) uint32_t u32x4;

__device__ __forceinline__ short f2bf(float f) {
    union { float f; uint32_t u; } x; x.f = f;
    uint32_t r = x.u + 0x7fffu + ((x.u >> 16) & 1u);   // RNE
    return (short)(r >> 16);
}

__device__ __forceinline__ void async_copy16(void* lds, const void* g) {
    __builtin_amdgcn_global_load_lds(
        (const __attribute__((address_space(1))) void*)g,
        (__attribute__((address_space(3))) void*)lds, 16, 0, 0);
}

// ---------------- prep: cast x/ctx -> bf16  |  4x weight transpose-cast  |  pool ----------------
// One dispatch, blockIdx-partitioned (all three parts independent, input-only).
#define NB_CAST 16384            // 2*n4/256, exact
#define NB_TC   2048             // 4 matrices x 512 tiles
#define NB_POOL 64               // 32 chunks x 2 batches
__global__ __launch_bounds__(256) void prep_kernel(
        const float* __restrict__ x, const float* __restrict__ ctx,
        const float* __restrict__ Wq, const float* __restrict__ Wk,
        const float* __restrict__ Wv, const float* __restrict__ Wout,
        short* __restrict__ x_bf, short* __restrict__ c_bf,
        short* __restrict__ Wqt, short* __restrict__ Wkvt, short* __restrict__ Wot,
        float* __restrict__ part, float scale_q) {
    __shared__ float tile[32][33];
    int blk = blockIdx.x, t = threadIdx.x;
    if (blk < NB_CAST) {
        // -------- cast fp32 -> bf16, x then ctx --------
        const int n4 = BATCH * N_TOK * QDIM / 4;
        int i = blk * 256 + t;
        bool first = i < n4;
        const float* s = first ? x : ctx;
        short* d = first ? x_bf : c_bf;
        int j = first ? i : i - n4;
        float4 v = ((const float4*)s)[j];
        ((short4*)d)[j] = make_short4(f2bf(v.x), f2bf(v.y), f2bf(v.z), f2bf(v.w));
    } else if (blk < NB_CAST + NB_TC) {
        // -------- weight transpose-cast --------
        int rel = blk - NB_CAST;
        int z = rel >> 9, bid = rel & 511;
        const float* W; short* Wt; int K, N; float scale = 1.f;
        if (z == 0)      { W = Wq;   Wt = Wqt;  K = QDIM;  N = INNER; scale = scale_q; }
        else if (z == 1) { W = Wk;   Wt = Wkvt; K = CDIM;  N = INNER; }
        else if (z == 2) { W = Wv;   Wt = Wkvt + (size_t)INNER * CDIM; K = CDIM; N = INNER; }
        else             { W = Wout; Wt = Wot;  K = INNER; N = QDIM; }
        int ntn = N >> 5;
        int n0 = (bid & (ntn - 1)) * 32, k0 = (bid / ntn) * 32;
        int tx = t & 31, ty = t >> 5;
        for (int r = ty; r < 32; r += 8)
            tile[r][tx] = W[(size_t)(k0 + r) * N + n0 + tx];
        __syncthreads();
        for (int r = ty; r < 32; r += 8)
            Wt[(size_t)(n0 + r) * K + k0 + tx] = f2bf(tile[tx][r] * scale);
    } else {
        // -------- pooled mean partial sums over 128-row chunks --------
        int rel = blk - NB_CAST - NB_TC;
        int c = rel & 31, b = rel >> 5;
        float s0 = 0.f, s1 = 0.f, s2 = 0.f, s3 = 0.f;
        const float* xp = x + ((size_t)b * N_TOK + c * 128) * QDIM;
        for (int n = 0; n < 128; n++) {
            const float* row = xp + (size_t)n * QDIM;
            s0 += row[t];
            s1 += row[256 + t];
            s2 += row[512 + t];
            s3 += row[768 + t];
        }
        float* pp = part + ((size_t)b * 32 + c) * QDIM;
        pp[t] = s0; pp[256 + t] = s1; pp[512 + t] = s2; pp[768 + t] = s3;
    }
}

// ------- V transpose+permute+mask: [BH][N1P][64] -> tiled [BH][132][80][32] -------
// Key permutation sigma'(p) = (p>>3)*4 + (p&3) + ((p>>2)&1)*16 matches the
// lane-local P layout produced by swapped QK^T (S^T = mfma(K,Q)): tile col p
// holds key sigma'(p). Slot-swizzle (16B slot ^ ((d>>1)&3)) unchanged; mask
// row 64 and zero rows are swizzle fixed points. Blocks 129..131 write zero pad tiles.
__global__ __launch_bounds__(256) void transpose_v_kernel(
        const short* __restrict__ vin, short* __restrict__ vout,
        const int* __restrict__ mask) {
    __shared__ short tile[32][65];
    __shared__ int mloc[32];
    int bh = blockIdx.z, b = bh >> 3;
    int j0 = blockIdx.x * 32, jb = blockIdx.x;
    int tx = threadIdx.x & 63, ty = threadIdx.x >> 6;       // ty 0..3
    const short* src = vin + (size_t)bh * N1P * DH;
    if (j0 < N1P) {
        for (int r = ty; r < 32; r += 4)
            tile[r][tx] = src[(size_t)(j0 + r) * DH + tx];
    }
    if (threadIdx.x < 32) {
        int j = j0 + threadIdx.x;
        mloc[threadIdx.x] = (j < N1) ? mask[b * N1 + j] : 0;
    }
    __syncthreads();
    int tp = threadIdx.x & 31, dy = threadIdx.x >> 5;       // dy 0..7
    int s = (tp >> 3) * 4 + (tp & 3) + ((tp >> 2) & 1) * 16;   // sigma'(p)
    bool mk = mloc[s] != 0;
    short* dst = vout + ((size_t)bh * NJBP + jb) * VTILE_SH;
    for (int d = dy; d < DH; d += 8) {
        int swz = (((tp >> 3) ^ ((d >> 1) & 3)) << 3) | (tp & 7);
        dst[d * 32 + swz] = mk ? tile[s][d] : (short)0;
    }
    if (dy == 0) dst[64 * 32 + tp] = mk ? (short)0x3F80 : (short)0;  // bf16 1.0
    if (dy == 1)  // zero rows 65..79 to keep frag-4 plane defined
        for (int d = 65; d < 80; d++) dst[d * 32 + tp] = 0;
}

// ---------------- fused QKV bf16 MFMA GEMM + bg projections ----------------
// Blocks 0..767: GEMM (XCD-contiguous remap, 776%8==0 bijective).
// Blocks 768..775: bg stage-2 (pooled mean finish + fp32 bg K/V rows + K zero pads).
// bg depends only on `part` (prep); disjoint writes from GEMM blocks.
__global__ __launch_bounds__(256) void qkv_gemm_kernel(
        const short* __restrict__ x_bf, const short* __restrict__ c_bf,
        const short* __restrict__ Wqt, const short* __restrict__ Wkvt,
        const float* __restrict__ part, const float* __restrict__ Wkbg,
        const float* __restrict__ Wvbg,
        short* __restrict__ q_bf, short* __restrict__ k_bf, short* __restrict__ v_tmp) {
    __shared__ short As[128 * 32];
    __shared__ short Bs[128 * 32];
    __shared__ float pooled[QDIM];
    const int t = threadIdx.x;
    int bid = (blockIdx.x & 7) * 97 + (blockIdx.x >> 3);    // XCD-contiguous remap, 776=8*97

    if (bid >= 768) {
        // ---------------- bg branch ----------------
        int sub = bid - 768;                                 // 0..7
        int b = sub & 1, jb = sub >> 1;                      // jb 0..3
        for (int d = t; d < QDIM; d += 256) {
            float s = 0.f;
            for (int c = 0; c < 32; c++) s += part[((size_t)b * 32 + c) * QDIM + d];
            pooled[d] = s * (1.f / (float)N_TOK);
        }
        __syncthreads();
        int flat = jb * 256 + t;          // 0..1023
        int matv = flat >> 9;             // 0: k, 1: v
        int o = flat & 511;
        const float* W = matv ? Wvbg : Wkbg;
        float s = 0.f;
        for (int k = 0; k < QDIM; k++) s += pooled[k] * W[(size_t)k * INNER + o];
        int h = o >> 6, d = o & 63;
        if (matv) {
            v_tmp[(((size_t)(b * NH + h)) * N1P + N_TOK) * DH + d] = f2bf(s);
        } else {
            // bg key row: tile 128, r=0 (swizzle fixed point)
            k_bf[((size_t)(b * NH + h)) * NJBP * KTILE_SH + 128 * KTILE_SH
                 + (d >> 5) * 1024 + (d & 31)] = f2bf(s);
        }
        if (jb == 0) {
            // zero padding key rows 4097..4127 (tile 128, r=1..31)
            for (int idx = t; idx < NH * 31 * DH; idx += 256) {
                int h2 = idx / (31 * DH);
                int r2 = idx % (31 * DH);
                int rr = 1 + r2 / DH;
                int d2 = r2 % DH;
                k_bf[((size_t)(b * NH + h2)) * NJBP * KTILE_SH + 128 * KTILE_SH
                     + (d2 >> 5) * 1024 + rr * 32 + (d2 & 31)] = 0;
            }
            // zero pad tiles 129..131 entirely (K=0 -> p=1, but V=0 & maskrow=0)
            for (int idx = t; idx < NH * 3 * KTILE_SH; idx += 256) {
                int h2 = idx / (3 * KTILE_SH);
                int r2 = idx % (3 * KTILE_SH);
                k_bf[((size_t)(b * NH + h2)) * NJBP * KTILE_SH + 129 * KTILE_SH + r2] = 0;
            }
        }
        return;
    }

    // ---------------- GEMM branch ----------------
    const int lane = t & 63, w = t >> 6;
    const int wr = w >> 1, wc = w & 1;
    const int lo = lane & 15, g = lane >> 4;
    const int arow = lane >> 2;
    const int ac8 = (lane & 3) * 8;

    const short *A, *W;
    int m0, n0, which;
    if (bid < 256) { A = x_bf; W = Wqt;  m0 = (bid >> 2) * 128; n0 = (bid & 3) * 128; which = 0; }
    else { int i = bid - 256; A = c_bf; W = Wkvt; m0 = (i >> 3) * 128; n0 = (i & 7) * 128;
           which = (n0 < 512) ? 1 : 2; }

    f32x4 acc[4][4] = {};
    for (int k0 = 0; k0 < 1024; k0 += 32) {
        for (int q = 0; q < 2; q++) {
            int seg = w * 2 + q;
            async_copy16(&As[seg * 512], A + (size_t)(m0 + seg * 16 + arow) * 1024 + k0 + ac8);
            async_copy16(&Bs[seg * 512], W + (size_t)(n0 + seg * 16 + arow) * 1024 + k0 + ac8);
        }
        __syncthreads();
        short8 af[4], bfv[4];
        #pragma unroll
        for (int i = 0; i < 4; i++)
            af[i] = *(const short8*)&As[(wr * 64 + i * 16 + lo) * 32 + g * 8];
        #pragma unroll
        for (int j = 0; j < 4; j++)
            bfv[j] = *(const short8*)&Bs[(wc * 64 + j * 16 + lo) * 32 + g * 8];
        #pragma unroll
        for (int i = 0; i < 4; i++)
            #pragma unroll
            for (int j = 0; j < 4; j++)
                acc[i][j] = __builtin_amdgcn_mfma_f32_16x16x32_bf16(af[i], bfv[j], acc[i][j], 0, 0, 0);
        __syncthreads();
    }

    if (which == 0) {
        #pragma unroll
        for (int i = 0; i < 4; i++)
            #pragma unroll
            for (int j = 0; j < 4; j++) {
                int row = m0 + wr * 64 + i * 16 + g * 4;
                int col0 = n0 + wc * 64 + j * 16 + lo;
                int h = col0 >> 6, d = col0 & 63;
                f32x4 v = acc[i][j];
                #pragma unroll
                for (int r = 0; r < 4; r++) {
                    int m = row + r;
                    int b = m >> 12, ii = m & 4095;
                    q_bf[(((size_t)(b * NH + h)) * N_TOK + ii) * DH + d] = f2bf(v[r]);
                }
            }
    } else if (which == 1) {
        #pragma unroll
        for (int i = 0; i < 4; i++)
            #pragma unroll
            for (int j = 0; j < 4; j++) {
                int row = m0 + wr * 64 + i * 16 + g * 4;
                int col0 = n0 + wc * 64 + j * 16 + lo;
                int h = col0 >> 6, d = col0 & 63;   // K: tiled layout, slot-swizzled
                f32x4 v = acc[i][j];
                #pragma unroll
                for (int r = 0; r < 4; r++) {
                    int m = row + r;
                    int b = m >> 12, ii = m & 4095;
                    int off = (d >> 5) * 1024 + (ii & 31) * 32 + (d & 31);
                    off ^= ((ii >> 1) & 3) << 3;   // carry-free slot swizzle
                    k_bf[((size_t)(b * NH + h)) * NJBP * KTILE_SH + (ii >> 5) * KTILE_SH
                         + off] = f2bf(v[r]);
                }
            }
    } else {
        #pragma unroll
        for (int i = 0; i < 4; i++)
            #pragma unroll
            for (int j = 0; j < 4; j++) {
                int row = m0 + wr * 64 + i * 16 + g * 4;
                int col0 = n0 + wc * 64 + j * 16 + lo;
                int col = col0 - 512;
                int h = col >> 6, d = col & 63;
                f32x4 v = acc[i][j];
                #pragma unroll
                for (int r = 0; r < 4; r++) {
                    int m = row + r;
                    int b = m >> 12, ii = m & 4095;
                    v_tmp[(((size_t)(b * NH + h)) * N1P + ii) * DH + d] = f2bf(v[r]);
                }
            }
    }
}

// ---------------- out-projection GEMM: out = O @ Wot^T + bias (f32) ----------------
// 1D grid 512, XCD-contiguous remap (512 = 8*64, bijective).
__global__ __launch_bounds__(256) void out_gemm_kernel(
        const short* __restrict__ A, const short* __restrict__ Wt,
        float* __restrict__ outf, const float* __restrict__ bias) {
    __shared__ short As[128 * 32];
    __shared__ short Bs[128 * 32];
    const int t = threadIdx.x;
    const int lane = t & 63, w = t >> 6;
    const int wr = w >> 1, wc = w & 1;
    const int lo = lane & 15, g = lane >> 4;
    const int arow = lane >> 2;
    const int ac8 = (lane & 3) * 8;
    const int bid = (blockIdx.x & 7) * 64 + (blockIdx.x >> 3);
    const int m0 = (bid & 63) * 128, n0 = (bid >> 6) * 128;

    f32x4 acc[4][4] = {};
    for (int k0 = 0; k0 < INNER; k0 += 32) {
        for (int q = 0; q < 2; q++) {
            int seg = w * 2 + q;
            async_copy16(&As[seg * 512], A + (size_t)(m0 + seg * 16 + arow) * INNER + k0 + ac8);
            async_copy16(&Bs[seg * 512], Wt + (size_t)(n0 + seg * 16 + arow) * INNER + k0 + ac8);
        }
        __syncthreads();
        short8 af[4], bfv[4];
        #pragma unroll
        for (int i = 0; i < 4; i++)
            af[i] = *(const short8*)&As[(wr * 64 + i * 16 + lo) * 32 + g * 8];
        #pragma unroll
        for (int j = 0; j < 4; j++)
            bfv[j] = *(const short8*)&Bs[(wc * 64 + j * 16 + lo) * 32 + g * 8];
        #pragma unroll
        for (int i = 0; i < 4; i++)
            #pragma unroll
            for (int j = 0; j < 4; j++)
                acc[i][j] = __builtin_amdgcn_mfma_f32_16x16x32_bf16(af[i], bfv[j], acc[i][j], 0, 0, 0);
        __syncthreads();
    }
    #pragma unroll
    for (int i = 0; i < 4; i++)
        #pragma unroll
        for (int j = 0; j < 4; j++) {
            int row = m0 + wr * 64 + i * 16 + g * 4;
            int col = n0 + wc * 64 + j * 16 + lo;
            f32x4 v = acc[i][j];
            #pragma unroll
            for (int r = 0; r < 4; r++)
                outf[(size_t)(row + r) * QDIM + col] = v[r] + bias[col];
        }
}

// ---------------- flash attention: swapped QK^T, reg-local P, grid 1024 ----------------
// ROUND 8: the grid (512 = 2 blocks/CU) was the occupancy cap, not LDS/barriers
// (r7: 33 vs 65 barriers flat). Now 1024 blocks x 4 waves x 16 Q-rows:
// 4 blocks/CU (LDS 36.8KB x 4 = 147KB), 4 waves/SIMD. Per-CU MFMA/VALU totals
// unchanged; DS traffic doubles but stays under the MFMA pipe floor. 2 tiles/iter,
// 66 iterations. setprio(1) around compute (T5).
__global__ __launch_bounds__(256, 4) void attn_kernel(
        const short* __restrict__ qb,   // [BH][4096][64], scaled by 0.125*log2e via Wq
        const short* __restrict__ kb,   // [BH][132][2][32][32] tiled, swizzled
        const short* __restrict__ vtb,  // [BH][132][80][32], sigma'-permuted, masked, swizzled
        short* __restrict__ ob) {       // [B*4096][512]
    const int t = threadIdx.x, lane = t & 63, w = t >> 6;
    const int lo = lane & 15, g = lane >> 4;
    const int gs = g ^ ((lo >> 1) & 3);                      // bank-conflict-free slot
    const int id = blockIdx.x;
    const int h = id & 7, b = (id >> 3) & 1, qt = id >> 4;   // qt 0..63
    const int q0 = qt * 64 + w * 16;
    const size_t bh = (size_t)(b * NH + h);

    const short* qp = qb + (bh * N_TOK + q0 + lo) * DH;
    short8 qa0 = *(const short8*)(qp + g * 8);
    short8 qa1 = *(const short8*)(qp + 32 + g * 8);

    __shared__ short Kl[2][2][KTILE_SH];
    __shared__ short Vl[2][2][VTILE_SH];

    const short* ksrc = kb + bh * (size_t)NJBP * KTILE_SH + w * 512 + lane * 8;
    const short* vsrc = vtb + bh * (size_t)NJBP * VTILE_SH + w * 512 + lane * 8;

    f32x4 o[5] = {};
    f32x4 z = {};

    // prologue: stage tiles 0,1 -> buf 0
    async_copy16(&Kl[0][0][w * 512], ksrc);
    async_copy16(&Vl[0][0][w * 512], vsrc);
    async_copy16(&Kl[0][1][w * 512], ksrc + KTILE_SH);
    async_copy16(&Vl[0][1][w * 512], vsrc + VTILE_SH);
    if (w == 0) {
        async_copy16(&Vl[0][0][2048], vsrc + 2048);
        async_copy16(&Vl[0][1][2048], vsrc + VTILE_SH + 2048);
    }
    __syncthreads();

    for (int it = 0; it < 66; ++it) {
        const int cur = it & 1;
        if (it < 65) {
            const short* ks = ksrc + (size_t)(2 * it + 2) * KTILE_SH;
            const short* vs = vsrc + (size_t)(2 * it + 2) * VTILE_SH;
            async_copy16(&Kl[cur ^ 1][0][w * 512], ks);
            async_copy16(&Vl[cur ^ 1][0][w * 512], vs);
            async_copy16(&Kl[cur ^ 1][1][w * 512], ks + KTILE_SH);
            async_copy16(&Vl[cur ^ 1][1][w * 512], vs + VTILE_SH);
            if (w == 0) {
                async_copy16(&Vl[cur ^ 1][0][2048], vs + 2048);
                async_copy16(&Vl[cur ^ 1][1][2048], vs + VTILE_SH + 2048);
            }
        }
        #pragma unroll
        for (int sub = 0; sub < 2; ++sub) {
            const short* kl = &Kl[cur][sub][0];
            const short* vl = &Vl[cur][sub][0];
            __builtin_amdgcn_s_setprio(1);
            // K frags: [key-half kh][dh-half hh] (swizzled slot gs)
            short8 kf00 = *(const short8*)&kl[(lo) * 32 + gs * 8];
            short8 kf01 = *(const short8*)&kl[1024 + (lo) * 32 + gs * 8];
            short8 kf10 = *(const short8*)&kl[(16 + lo) * 32 + gs * 8];
            short8 kf11 = *(const short8*)&kl[1024 + (16 + lo) * 32 + gs * 8];
            // V frags
            short8 vfr[5];
            #pragma unroll
            for (int f = 0; f < 5; f++)
                vfr[f] = *(const short8*)&vl[(f * 16 + lo) * 32 + gs * 8];
            // swapped QK^T: lane (lo,g) holds P[q=lo][k=g*4+r, 16+g*4+r]
            f32x4 s0 = __builtin_amdgcn_mfma_f32_16x16x32_bf16(kf00, qa0, z, 0, 0, 0);
            s0 = __builtin_amdgcn_mfma_f32_16x16x32_bf16(kf01, qa1, s0, 0, 0, 0);
            f32x4 s1 = __builtin_amdgcn_mfma_f32_16x16x32_bf16(kf10, qa0, z, 0, 0, 0);
            s1 = __builtin_amdgcn_mfma_f32_16x16x32_bf16(kf11, qa1, s1, 0, 0, 0);
            // exp2 + pack to PV A-fragment entirely in registers
            uint32_t u0 = __float_as_uint(__builtin_amdgcn_exp2f(s0[0])) + 0x8000u;
            uint32_t u1 = __float_as_uint(__builtin_amdgcn_exp2f(s0[1])) + 0x8000u;
            uint32_t u2 = __float_as_uint(__builtin_amdgcn_exp2f(s0[2])) + 0x8000u;
            uint32_t u3 = __float_as_uint(__builtin_amdgcn_exp2f(s0[3])) + 0x8000u;
            uint32_t u4 = __float_as_uint(__builtin_amdgcn_exp2f(s1[0])) + 0x8000u;
            uint32_t u5 = __float_as_uint(__builtin_amdgcn_exp2f(s1[1])) + 0x8000u;
            uint32_t u6 = __float_as_uint(__builtin_amdgcn_exp2f(s1[2])) + 0x8000u;
            uint32_t u7 = __float_as_uint(__builtin_amdgcn_exp2f(s1[3])) + 0x8000u;
            u32x4 pr;
            pr[0] = __builtin_amdgcn_perm(u1, u0, 0x07060302u);   // keys g*4+0, g*4+1
            pr[1] = __builtin_amdgcn_perm(u3, u2, 0x07060302u);   // keys g*4+2, g*4+3
            pr[2] = __builtin_amdgcn_perm(u5, u4, 0x07060302u);   // keys 16+g*4+0,+1
            pr[3] = __builtin_amdgcn_perm(u7, u6, 0x07060302u);   // keys 16+g*4+2,+3
            short8 pa = __builtin_bit_cast(short8, pr);
            #pragma unroll
            for (int f = 0; f < 5; f++)
                o[f] = __builtin_amdgcn_mfma_f32_16x16x32_bf16(pa, vfr[f], o[f], 0, 0, 0);
            __builtin_amdgcn_s_setprio(0);
        }
        __syncthreads();
    }

    short* op = ob + ((size_t)(b * N_TOK) + q0) * INNER + h * DH;
    #pragma unroll
    for (int r = 0; r < 4; r++) {
        float l = __shfl(o[4][r], lane & 48);   // col 0 of frag4 = sum(p*mask)
        float inv = (l > 0.f) ? 1.f / l : 0.f;
        short* o_ = op + (size_t)(g * 4 + r) * INNER;
        o_[lo]      = f2bf(o[0][r] * inv);
        o_[16 + lo] = f2bf(o[1][r] * inv);
        o_[32 + lo] = f2bf(o[2][r] * inv);
        o_[48 + lo] = f2bf(o[3][r] * inv);
    }
}

extern "C" void kernel_launch(void* const* d_in, const int* in_sizes, int n_in,
                              void* d_out, int out_size, void* d_ws, size_t ws_size,
                              hipStream_t stream) {
    const float* x    = (const float*)d_in[0];
    const float* ctx  = (const float*)d_in[1];
    const int*   mask = (const int*)d_in[2];
    const float* Wq   = (const float*)d_in[3];
    const float* Wk   = (const float*)d_in[4];
    const float* Wv   = (const float*)d_in[5];
    const float* Wkbg = (const float*)d_in[6];
    const float* Wvbg = (const float*)d_in[7];
    const float* Wout = (const float*)d_in[8];
    const float* bout = (const float*)d_in[9];
    float* out = (float*)d_out;

    char* p = (char*)d_ws;
    auto alloc = [&](size_t b) { char* r = p; p += (b + 255) & ~(size_t)255; return r; };
    short* x_bf  = (short*)alloc((size_t)BATCH * N_TOK * QDIM * 2);
    short* c_bf  = (short*)alloc((size_t)BATCH * N_TOK * CDIM * 2);
    short* Wqt   = (short*)alloc((size_t)INNER * QDIM * 2);
    short* Wkvt  = (short*)alloc((size_t)2 * INNER * CDIM * 2);   // Wk | Wv transposed
    short* Wot   = (short*)alloc((size_t)QDIM * INNER * 2);
    short* q_bf  = (short*)alloc((size_t)BATCH * NH * N_TOK * DH * 2);
    short* k_bf  = (short*)alloc((size_t)BATCH * NH * NJBP * KTILE_SH * 2);
    short* v_tmp = (short*)alloc((size_t)BATCH * NH * N1P * DH * 2);
    short* vt_bf = (short*)alloc((size_t)BATCH * NH * NJBP * VTILE_SH * 2);
    short* o_bf  = (short*)alloc((size_t)BATCH * N_TOK * INNER * 2);
    float* part  = (float*)alloc((size_t)BATCH * 32 * QDIM * 4);

    const float SCALE_Q = 0.125f * 1.4426950408889634f;  // fold scale*log2(e) into Wq

    prep_kernel<<<NB_CAST + NB_TC + NB_POOL, 256, 0, stream>>>(
        x, ctx, Wq, Wk, Wv, Wout, x_bf, c_bf, Wqt, Wkvt, Wot, part, SCALE_Q);

    qkv_gemm_kernel<<<776, 256, 0, stream>>>(
        x_bf, c_bf, Wqt, Wkvt, part, Wkbg, Wvbg, q_bf, k_bf, v_tmp);

    transpose_v_kernel<<<dim3(NJBP, 1, BATCH * NH), 256, 0, stream>>>(v_tmp, vt_bf, mask);

    attn_kernel<<<1024, 256, 0, stream>>>(q_bf, k_bf, vt_bf, o_bf);

    out_gemm_kernel<<<512, 256, 0, stream>>>(o_bf, Wot, out, bout);
}

// Round 9
// 303.565 us; speedup vs baseline: 1.0301x; 1.0301x over previous
//
#include <hip/hip_runtime.h>
#include <stdint.h>

#define N_TOK 4096
#define QDIM  1024
#define CDIM  1024
#define NH    8
#define DH    64
#define INNER 512
#define BATCH 2
#define N1    4097   // keys incl. background row
#define N1P   4128   // padded to /32
#define NJB   129    // real key tiles
#define NJBP  132    // padded; two key-halves of 66 tiles each
#define VROWS 80     // 64 V dims + mask row + 15 unused
#define KTILE_SH 2048  // shorts per K tile: [2][32][32]
#define VTILE_SH 2560  // shorts per V tile: [80][32]

typedef __attribute__((ext_vector_type(8))) short short8;
typedef __attribute__((ext_vector_type(4))) float f32x4;
typedef __attribute__((ext_vector_type(4))) uint32_t u32x4;

__device__ __forceinline__ short f2bf(float f) {
    union { float f; uint32_t u; } x; x.f = f;
    uint32_t r = x.u + 0x7fffu + ((x.u >> 16) & 1u);   // RNE
    return (short)(r >> 16);
}

__device__ __forceinline__ void async_copy16(void* lds, const void* g) {
    __builtin_amdgcn_global_load_lds(
        (const __attribute__((address_space(1))) void*)g,
        (__attribute__((address_space(3))) void*)lds, 16, 0, 0);
}

// ---------------- prep: cast x/ctx -> bf16  |  4x weight transpose-cast  |  pool ----------------
#define NB_CAST 16384            // 2*n4/256, exact
#define NB_TC   2048             // 4 matrices x 512 tiles
#define NB_POOL 64               // 32 chunks x 2 batches
__global__ __launch_bounds__(256) void prep_kernel(
        const float* __restrict__ x, const float* __restrict__ ctx,
        const float* __restrict__ Wq, const float* __restrict__ Wk,
        const float* __restrict__ Wv, const float* __restrict__ Wout,
        short* __restrict__ x_bf, short* __restrict__ c_bf,
        short* __restrict__ Wqt, short* __restrict__ Wkvt, short* __restrict__ Wot,
        float* __restrict__ part, float scale_q) {
    __shared__ float tile[32][33];
    int blk = blockIdx.x, t = threadIdx.x;
    if (blk < NB_CAST) {
        const int n4 = BATCH * N_TOK * QDIM / 4;
        int i = blk * 256 + t;
        bool first = i < n4;
        const float* s = first ? x : ctx;
        short* d = first ? x_bf : c_bf;
        int j = first ? i : i - n4;
        float4 v = ((const float4*)s)[j];
        ((short4*)d)[j] = make_short4(f2bf(v.x), f2bf(v.y), f2bf(v.z), f2bf(v.w));
    } else if (blk < NB_CAST + NB_TC) {
        int rel = blk - NB_CAST;
        int z = rel >> 9, bid = rel & 511;
        const float* W; short* Wt; int K, N; float scale = 1.f;
        if (z == 0)      { W = Wq;   Wt = Wqt;  K = QDIM;  N = INNER; scale = scale_q; }
        else if (z == 1) { W = Wk;   Wt = Wkvt; K = CDIM;  N = INNER; }
        else if (z == 2) { W = Wv;   Wt = Wkvt + (size_t)INNER * CDIM; K = CDIM; N = INNER; }
        else             { W = Wout; Wt = Wot;  K = INNER; N = QDIM; }
        int ntn = N >> 5;
        int n0 = (bid & (ntn - 1)) * 32, k0 = (bid / ntn) * 32;
        int tx = t & 31, ty = t >> 5;
        for (int r = ty; r < 32; r += 8)
            tile[r][tx] = W[(size_t)(k0 + r) * N + n0 + tx];
        __syncthreads();
        for (int r = ty; r < 32; r += 8)
            Wt[(size_t)(n0 + r) * K + k0 + tx] = f2bf(tile[tx][r] * scale);
    } else {
        int rel = blk - NB_CAST - NB_TC;
        int c = rel & 31, b = rel >> 5;
        float s0 = 0.f, s1 = 0.f, s2 = 0.f, s3 = 0.f;
        const float* xp = x + ((size_t)b * N_TOK + c * 128) * QDIM;
        for (int n = 0; n < 128; n++) {
            const float* row = xp + (size_t)n * QDIM;
            s0 += row[t];
            s1 += row[256 + t];
            s2 += row[512 + t];
            s3 += row[768 + t];
        }
        float* pp = part + ((size_t)b * 32 + c) * QDIM;
        pp[t] = s0; pp[256 + t] = s1; pp[512 + t] = s2; pp[768 + t] = s3;
    }
}

// ------- V transpose+permute+mask: [BH][N1P][64] -> tiled [BH][132][80][32] -------
// sigma'(p) = (p>>3)*4 + (p&3) + ((p>>2)&1)*16 matches swapped-QK^T lane-local P.
// Slot-swizzle (16B slot ^ ((d>>1)&3)); mask row 64 / zero rows are fixed points.
__global__ __launch_bounds__(256) void transpose_v_kernel(
        const short* __restrict__ vin, short* __restrict__ vout,
        const int* __restrict__ mask) {
    __shared__ short tile[32][65];
    __shared__ int mloc[32];
    int bh = blockIdx.z, b = bh >> 3;
    int j0 = blockIdx.x * 32, jb = blockIdx.x;
    int tx = threadIdx.x & 63, ty = threadIdx.x >> 6;       // ty 0..3
    const short* src = vin + (size_t)bh * N1P * DH;
    if (j0 < N1P) {
        for (int r = ty; r < 32; r += 4)
            tile[r][tx] = src[(size_t)(j0 + r) * DH + tx];
    }
    if (threadIdx.x < 32) {
        int j = j0 + threadIdx.x;
        mloc[threadIdx.x] = (j < N1) ? mask[b * N1 + j] : 0;
    }
    __syncthreads();
    int tp = threadIdx.x & 31, dy = threadIdx.x >> 5;       // dy 0..7
    int s = (tp >> 3) * 4 + (tp & 3) + ((tp >> 2) & 1) * 16;   // sigma'(p)
    bool mk = mloc[s] != 0;
    short* dst = vout + ((size_t)bh * NJBP + jb) * VTILE_SH;
    for (int d = dy; d < DH; d += 8) {
        int swz = (((tp >> 3) ^ ((d >> 1) & 3)) << 3) | (tp & 7);
        dst[d * 32 + swz] = mk ? tile[s][d] : (short)0;
    }
    if (dy == 0) dst[64 * 32 + tp] = mk ? (short)0x3F80 : (short)0;  // bf16 1.0
    if (dy == 1)
        for (int d = 65; d < 80; d++) dst[d * 32 + tp] = 0;
}

// ---------------- fused QKV bf16 MFMA GEMM + bg projections ----------------
__global__ __launch_bounds__(256) void qkv_gemm_kernel(
        const short* __restrict__ x_bf, const short* __restrict__ c_bf,
        const short* __restrict__ Wqt, const short* __restrict__ Wkvt,
        const float* __restrict__ part, const float* __restrict__ Wkbg,
        const float* __restrict__ Wvbg,
        short* __restrict__ q_bf, short* __restrict__ k_bf, short* __restrict__ v_tmp) {
    __shared__ short As[128 * 32];
    __shared__ short Bs[128 * 32];
    __shared__ float pooled[QDIM];
    const int t = threadIdx.x;
    int bid = (blockIdx.x & 7) * 97 + (blockIdx.x >> 3);    // XCD-contiguous remap, 776=8*97

    if (bid >= 768) {
        int sub = bid - 768;                                 // 0..7
        int b = sub & 1, jb = sub >> 1;                      // jb 0..3
        for (int d = t; d < QDIM; d += 256) {
            float s = 0.f;
            for (int c = 0; c < 32; c++) s += part[((size_t)b * 32 + c) * QDIM + d];
            pooled[d] = s * (1.f / (float)N_TOK);
        }
        __syncthreads();
        int flat = jb * 256 + t;          // 0..1023
        int matv = flat >> 9;             // 0: k, 1: v
        int o = flat & 511;
        const float* W = matv ? Wvbg : Wkbg;
        float s = 0.f;
        for (int k = 0; k < QDIM; k++) s += pooled[k] * W[(size_t)k * INNER + o];
        int h = o >> 6, d = o & 63;
        if (matv) {
            v_tmp[(((size_t)(b * NH + h)) * N1P + N_TOK) * DH + d] = f2bf(s);
        } else {
            k_bf[((size_t)(b * NH + h)) * NJBP * KTILE_SH + 128 * KTILE_SH
                 + (d >> 5) * 1024 + (d & 31)] = f2bf(s);
        }
        if (jb == 0) {
            for (int idx = t; idx < NH * 31 * DH; idx += 256) {
                int h2 = idx / (31 * DH);
                int r2 = idx % (31 * DH);
                int rr = 1 + r2 / DH;
                int d2 = r2 % DH;
                k_bf[((size_t)(b * NH + h2)) * NJBP * KTILE_SH + 128 * KTILE_SH
                     + (d2 >> 5) * 1024 + rr * 32 + (d2 & 31)] = 0;
            }
            for (int idx = t; idx < NH * 3 * KTILE_SH; idx += 256) {
                int h2 = idx / (3 * KTILE_SH);
                int r2 = idx % (3 * KTILE_SH);
                k_bf[((size_t)(b * NH + h2)) * NJBP * KTILE_SH + 129 * KTILE_SH + r2] = 0;
            }
        }
        return;
    }

    const int lane = t & 63, w = t >> 6;
    const int wr = w >> 1, wc = w & 1;
    const int lo = lane & 15, g = lane >> 4;
    const int arow = lane >> 2;
    const int ac8 = (lane & 3) * 8;

    const short *A, *W;
    int m0, n0, which;
    if (bid < 256) { A = x_bf; W = Wqt;  m0 = (bid >> 2) * 128; n0 = (bid & 3) * 128; which = 0; }
    else { int i = bid - 256; A = c_bf; W = Wkvt; m0 = (i >> 3) * 128; n0 = (i & 7) * 128;
           which = (n0 < 512) ? 1 : 2; }

    f32x4 acc[4][4] = {};
    for (int k0 = 0; k0 < 1024; k0 += 32) {
        for (int q = 0; q < 2; q++) {
            int seg = w * 2 + q;
            async_copy16(&As[seg * 512], A + (size_t)(m0 + seg * 16 + arow) * 1024 + k0 + ac8);
            async_copy16(&Bs[seg * 512], W + (size_t)(n0 + seg * 16 + arow) * 1024 + k0 + ac8);
        }
        __syncthreads();
        short8 af[4], bfv[4];
        #pragma unroll
        for (int i = 0; i < 4; i++)
            af[i] = *(const short8*)&As[(wr * 64 + i * 16 + lo) * 32 + g * 8];
        #pragma unroll
        for (int j = 0; j < 4; j++)
            bfv[j] = *(const short8*)&Bs[(wc * 64 + j * 16 + lo) * 32 + g * 8];
        #pragma unroll
        for (int i = 0; i < 4; i++)
            #pragma unroll
            for (int j = 0; j < 4; j++)
                acc[i][j] = __builtin_amdgcn_mfma_f32_16x16x32_bf16(af[i], bfv[j], acc[i][j], 0, 0, 0);
        __syncthreads();
    }

    if (which == 0) {
        #pragma unroll
        for (int i = 0; i < 4; i++)
            #pragma unroll
            for (int j = 0; j < 4; j++) {
                int row = m0 + wr * 64 + i * 16 + g * 4;
                int col0 = n0 + wc * 64 + j * 16 + lo;
                int h = col0 >> 6, d = col0 & 63;
                f32x4 v = acc[i][j];
                #pragma unroll
                for (int r = 0; r < 4; r++) {
                    int m = row + r;
                    int b = m >> 12, ii = m & 4095;
                    q_bf[(((size_t)(b * NH + h)) * N_TOK + ii) * DH + d] = f2bf(v[r]);
                }
            }
    } else if (which == 1) {
        #pragma unroll
        for (int i = 0; i < 4; i++)
            #pragma unroll
            for (int j = 0; j < 4; j++) {
                int row = m0 + wr * 64 + i * 16 + g * 4;
                int col0 = n0 + wc * 64 + j * 16 + lo;
                int h = col0 >> 6, d = col0 & 63;   // K: tiled layout, slot-swizzled
                f32x4 v = acc[i][j];
                #pragma unroll
                for (int r = 0; r < 4; r++) {
                    int m = row + r;
                    int b = m >> 12, ii = m & 4095;
                    int off = (d >> 5) * 1024 + (ii & 31) * 32 + (d & 31);
                    off ^= ((ii >> 1) & 3) << 3;   // carry-free slot swizzle
                    k_bf[((size_t)(b * NH + h)) * NJBP * KTILE_SH + (ii >> 5) * KTILE_SH
                         + off] = f2bf(v[r]);
                }
            }
    } else {
        #pragma unroll
        for (int i = 0; i < 4; i++)
            #pragma unroll
            for (int j = 0; j < 4; j++) {
                int row = m0 + wr * 64 + i * 16 + g * 4;
                int col0 = n0 + wc * 64 + j * 16 + lo;
                int col = col0 - 512;
                int h = col >> 6, d = col & 63;
                f32x4 v = acc[i][j];
                #pragma unroll
                for (int r = 0; r < 4; r++) {
                    int m = row + r;
                    int b = m >> 12, ii = m & 4095;
                    v_tmp[(((size_t)(b * NH + h)) * N1P + ii) * DH + d] = f2bf(v[r]);
                }
            }
    }
}

// ---------------- out-projection GEMM: out = O @ Wot^T + bias (f32) ----------------
__global__ __launch_bounds__(256) void out_gemm_kernel(
        const short* __restrict__ A, const short* __restrict__ Wt,
        float* __restrict__ outf, const float* __restrict__ bias) {
    __shared__ short As[128 * 32];
    __shared__ short Bs[128 * 32];
    const int t = threadIdx.x;
    const int lane = t & 63, w = t >> 6;
    const int wr = w >> 1, wc = w & 1;
    const int lo = lane & 15, g = lane >> 4;
    const int arow = lane >> 2;
    const int ac8 = (lane & 3) * 8;
    const int bid = (blockIdx.x & 7) * 64 + (blockIdx.x >> 3);
    const int m0 = (bid & 63) * 128, n0 = (bid >> 6) * 128;

    f32x4 acc[4][4] = {};
    for (int k0 = 0; k0 < INNER; k0 += 32) {
        for (int q = 0; q < 2; q++) {
            int seg = w * 2 + q;
            async_copy16(&As[seg * 512], A + (size_t)(m0 + seg * 16 + arow) * INNER + k0 + ac8);
            async_copy16(&Bs[seg * 512], Wt + (size_t)(n0 + seg * 16 + arow) * INNER + k0 + ac8);
        }
        __syncthreads();
        short8 af[4], bfv[4];
        #pragma unroll
        for (int i = 0; i < 4; i++)
            af[i] = *(const short8*)&As[(wr * 64 + i * 16 + lo) * 32 + g * 8];
        #pragma unroll
        for (int j = 0; j < 4; j++)
            bfv[j] = *(const short8*)&Bs[(wc * 64 + j * 16 + lo) * 32 + g * 8];
        #pragma unroll
        for (int i = 0; i < 4; i++)
            #pragma unroll
            for (int j = 0; j < 4; j++)
                acc[i][j] = __builtin_amdgcn_mfma_f32_16x16x32_bf16(af[i], bfv[j], acc[i][j], 0, 0, 0);
        __syncthreads();
    }
    #pragma unroll
    for (int i = 0; i < 4; i++)
        #pragma unroll
        for (int j = 0; j < 4; j++) {
            int row = m0 + wr * 64 + i * 16 + g * 4;
            int col = n0 + wc * 64 + j * 16 + lo;
            f32x4 v = acc[i][j];
            #pragma unroll
            for (int r = 0; r < 4; r++)
                outf[(size_t)(row + r) * QDIM + col] = v[r] + bias[col];
        }
}

// ---------------- flash attention: in-block KEY-SPLIT, swapped QK^T, reg-local P ----------------
// ROUND 9: r8 showed 16-row waves are DS-bound (frag reads are per-wave,
// tile-invariant); r7 showed 32-row waves are work-capped at 2 waves/SIMD.
// Resolution: 8 waves/block, waves 0-3 own key tiles 0..65, waves 4-7 own
// 66..131, every wave keeps 32 Q-rows (DS-optimal). 16 waves/CU = 4/SIMD with
// the SAME total DS/MFMA/VALU as r7. exp2-softmax is max-free, so halves
// combine by pure addition (numerator frags + mask-row denominators) via a
// 40KB LDS exchange after the main loop — no extra kernel, no HBM partials.
__global__ __launch_bounds__(512, 4) void attn_kernel(
        const short* __restrict__ qb,   // [BH][4096][64], scaled by 0.125*log2e via Wq
        const short* __restrict__ kb,   // [BH][132][2][32][32] tiled, swizzled
        const short* __restrict__ vtb,  // [BH][132][80][32], sigma'-permuted, masked, swizzled
        short* __restrict__ ob) {       // [B*4096][512]
    const int t = threadIdx.x, lane = t & 63, w = t >> 6;    // w 0..7
    const int w4 = w & 3, half = w >> 2;
    const int lo = lane & 15, g = lane >> 4;
    const int gs = g ^ ((lo >> 1) & 3);                      // bank-conflict-free slot
    const int id = blockIdx.x;
    const int h = id & 7, b = (id >> 3) & 1, qt = id >> 4;   // qt 0..31
    const int q0 = qt * 128 + w4 * 32;
    const size_t bh = (size_t)(b * NH + h);

    const short* qp = qb + (bh * N_TOK + q0 + lo) * DH;
    short8 qa[2][2];
    qa[0][0] = *(const short8*)(qp + g * 8);
    qa[0][1] = *(const short8*)(qp + 32 + g * 8);
    qa[1][0] = *(const short8*)(qp + 16 * DH + g * 8);
    qa[1][1] = *(const short8*)(qp + 16 * DH + 32 + g * 8);

    // [half][buf][sub] carved from one LDS pool; reused as f32 exchange at the end
    __shared__ short lds[36864];                             // 73728 B
    short* Kb = lds;                                         // 8 x 2048
    short* Vb = lds + 16384;                                 // 8 x 2560
    float* xch = (float*)lds;

    const int tb = half * 66;                                // this half's tile base
    const short* ksrc = kb + bh * (size_t)NJBP * KTILE_SH + (size_t)tb * KTILE_SH
                        + w4 * 512 + lane * 8;
    const short* vsrc = vtb + bh * (size_t)NJBP * VTILE_SH + (size_t)tb * VTILE_SH
                        + w4 * 512 + lane * 8;

    f32x4 o[2][5] = {};
    f32x4 z = {};

    // prologue: stage this half's tiles 0,1 -> buf 0
    #pragma unroll
    for (int s = 0; s < 2; s++) {
        short* kd = Kb + ((half * 2 + 0) * 2 + s) * 2048;
        short* vd = Vb + ((half * 2 + 0) * 2 + s) * 2560;
        async_copy16(kd + w4 * 512, ksrc + (size_t)s * KTILE_SH);
        async_copy16(vd + w4 * 512, vsrc + (size_t)s * VTILE_SH);
        if (w4 == 0) async_copy16(vd + 2048, vsrc + (size_t)s * VTILE_SH + 2048);
    }
    __syncthreads();

    for (int it = 0; it < 33; ++it) {
        const int cur = it & 1;
        if (it < 32) {
            const short* ks = ksrc + (size_t)(2 * it + 2) * KTILE_SH;
            const short* vs = vsrc + (size_t)(2 * it + 2) * VTILE_SH;
            #pragma unroll
            for (int s = 0; s < 2; s++) {
                short* kd = Kb + ((half * 2 + (cur ^ 1)) * 2 + s) * 2048;
                short* vd = Vb + ((half * 2 + (cur ^ 1)) * 2 + s) * 2560;
                async_copy16(kd + w4 * 512, ks + (size_t)s * KTILE_SH);
                async_copy16(vd + w4 * 512, vs + (size_t)s * VTILE_SH);
                if (w4 == 0) async_copy16(vd + 2048, vs + (size_t)s * VTILE_SH + 2048);
            }
        }
        #pragma unroll
        for (int sub = 0; sub < 2; ++sub) {
            const short* kl = Kb + ((half * 2 + cur) * 2 + sub) * 2048;
            const short* vl = Vb + ((half * 2 + cur) * 2 + sub) * 2560;
            __builtin_amdgcn_s_setprio(1);
            short8 kf00 = *(const short8*)&kl[(lo) * 32 + gs * 8];
            short8 kf01 = *(const short8*)&kl[1024 + (lo) * 32 + gs * 8];
            short8 kf10 = *(const short8*)&kl[(16 + lo) * 32 + gs * 8];
            short8 kf11 = *(const short8*)&kl[1024 + (16 + lo) * 32 + gs * 8];
            short8 vfr[5];
            #pragma unroll
            for (int f = 0; f < 5; f++)
                vfr[f] = *(const short8*)&vl[(f * 16 + lo) * 32 + gs * 8];
            #pragma unroll
            for (int rg = 0; rg < 2; rg++) {
                // swapped QK^T: lane (lo,g) holds P[q=lo][k=g*4+r, 16+g*4+r]
                f32x4 s0 = __builtin_amdgcn_mfma_f32_16x16x32_bf16(kf00, qa[rg][0], z, 0, 0, 0);
                s0 = __builtin_amdgcn_mfma_f32_16x16x32_bf16(kf01, qa[rg][1], s0, 0, 0, 0);
                f32x4 s1 = __builtin_amdgcn_mfma_f32_16x16x32_bf16(kf10, qa[rg][0], z, 0, 0, 0);
                s1 = __builtin_amdgcn_mfma_f32_16x16x32_bf16(kf11, qa[rg][1], s1, 0, 0, 0);
                uint32_t u0 = __float_as_uint(__builtin_amdgcn_exp2f(s0[0])) + 0x8000u;
                uint32_t u1 = __float_as_uint(__builtin_amdgcn_exp2f(s0[1])) + 0x8000u;
                uint32_t u2 = __float_as_uint(__builtin_amdgcn_exp2f(s0[2])) + 0x8000u;
                uint32_t u3 = __float_as_uint(__builtin_amdgcn_exp2f(s0[3])) + 0x8000u;
                uint32_t u4 = __float_as_uint(__builtin_amdgcn_exp2f(s1[0])) + 0x8000u;
                uint32_t u5 = __float_as_uint(__builtin_amdgcn_exp2f(s1[1])) + 0x8000u;
                uint32_t u6 = __float_as_uint(__builtin_amdgcn_exp2f(s1[2])) + 0x8000u;
                uint32_t u7 = __float_as_uint(__builtin_amdgcn_exp2f(s1[3])) + 0x8000u;
                u32x4 pr;
                pr[0] = __builtin_amdgcn_perm(u1, u0, 0x07060302u);
                pr[1] = __builtin_amdgcn_perm(u3, u2, 0x07060302u);
                pr[2] = __builtin_amdgcn_perm(u5, u4, 0x07060302u);
                pr[3] = __builtin_amdgcn_perm(u7, u6, 0x07060302u);
                short8 pa = __builtin_bit_cast(short8, pr);
                #pragma unroll
                for (int f = 0; f < 5; f++)
                    o[rg][f] = __builtin_amdgcn_mfma_f32_16x16x32_bf16(pa, vfr[f], o[rg][f], 0, 0, 0);
            }
            __builtin_amdgcn_s_setprio(0);
        }
        __syncthreads();
    }

    // ---- combine halves: waves 4-7 dump partials (num frags + mask-row den), waves 0-3 add ----
    if (half == 1) {
        #pragma unroll
        for (int rg = 0; rg < 2; rg++)
            #pragma unroll
            for (int f = 0; f < 5; f++)
                *(f32x4*)&xch[(((w4 * 2 + rg) * 5 + f) * 64 + lane) * 4] = o[rg][f];
    }
    __syncthreads();
    if (half == 0) {
        #pragma unroll
        for (int rg = 0; rg < 2; rg++)
            #pragma unroll
            for (int f = 0; f < 5; f++) {
                f32x4 p = *(const f32x4*)&xch[(((w4 * 2 + rg) * 5 + f) * 64 + lane) * 4];
                o[rg][f] += p;
            }
        short* op = ob + ((size_t)(b * N_TOK) + q0) * INNER + h * DH;
        #pragma unroll
        for (int rg = 0; rg < 2; rg++)
            #pragma unroll
            for (int r = 0; r < 4; r++) {
                float l = __shfl(o[rg][4][r], lane & 48);   // col 0 of frag4 = sum(p*mask)
                float inv = (l > 0.f) ? 1.f / l : 0.f;
                short* o_ = op + (size_t)(rg * 16 + g * 4 + r) * INNER;
                o_[lo]      = f2bf(o[rg][0][r] * inv);
                o_[16 + lo] = f2bf(o[rg][1][r] * inv);
                o_[32 + lo] = f2bf(o[rg][2][r] * inv);
                o_[48 + lo] = f2bf(o[rg][3][r] * inv);
            }
    }
}

extern "C" void kernel_launch(void* const* d_in, const int* in_sizes, int n_in,
                              void* d_out, int out_size, void* d_ws, size_t ws_size,
                              hipStream_t stream) {
    const float* x    = (const float*)d_in[0];
    const float* ctx  = (const float*)d_in[1];
    const int*   mask = (const int*)d_in[2];
    const float* Wq   = (const float*)d_in[3];
    const float* Wk   = (const float*)d_in[4];
    const float* Wv   = (const float*)d_in[5];
    const float* Wkbg = (const float*)d_in[6];
    const float* Wvbg = (const float*)d_in[7];
    const float* Wout = (const float*)d_in[8];
    const float* bout = (const float*)d_in[9];
    float* out = (float*)d_out;

    char* p = (char*)d_ws;
    auto alloc = [&](size_t b) { char* r = p; p += (b + 255) & ~(size_t)255; return r; };
    short* x_bf  = (short*)alloc((size_t)BATCH * N_TOK * QDIM * 2);
    short* c_bf  = (short*)alloc((size_t)BATCH * N_TOK * CDIM * 2);
    short* Wqt   = (short*)alloc((size_t)INNER * QDIM * 2);
    short* Wkvt  = (short*)alloc((size_t)2 * INNER * CDIM * 2);   // Wk | Wv transposed
    short* Wot   = (short*)alloc((size_t)QDIM * INNER * 2);
    short* q_bf  = (short*)alloc((size_t)BATCH * NH * N_TOK * DH * 2);
    short* k_bf  = (short*)alloc((size_t)BATCH * NH * NJBP * KTILE_SH * 2);
    short* v_tmp = (short*)alloc((size_t)BATCH * NH * N1P * DH * 2);
    short* vt_bf = (short*)alloc((size_t)BATCH * NH * NJBP * VTILE_SH * 2);
    short* o_bf  = (short*)alloc((size_t)BATCH * N_TOK * INNER * 2);
    float* part  = (float*)alloc((size_t)BATCH * 32 * QDIM * 4);

    const float SCALE_Q = 0.125f * 1.4426950408889634f;  // fold scale*log2(e) into Wq

    prep_kernel<<<NB_CAST + NB_TC + NB_POOL, 256, 0, stream>>>(
        x, ctx, Wq, Wk, Wv, Wout, x_bf, c_bf, Wqt, Wkvt, Wot, part, SCALE_Q);

    qkv_gemm_kernel<<<776, 256, 0, stream>>>(
        x_bf, c_bf, Wqt, Wkvt, part, Wkbg, Wvbg, q_bf, k_bf, v_tmp);

    transpose_v_kernel<<<dim3(NJBP, 1, BATCH * NH), 256, 0, stream>>>(v_tmp, vt_bf, mask);

    attn_kernel<<<512, 512, 0, stream>>>(q_bf, k_bf, vt_bf, o_bf);

    out_gemm_kernel<<<512, 256, 0, stream>>>(o_bf, Wot, out, bout);
}